// Round 19
// baseline (369.555 us; speedup 1.0000x reference)
//
#include <hip/hip_runtime.h>
#include <hip/hip_bf16.h>

// B=32, Q=16, F=4096, E=256, NL=8, L=2 residual layers per mapper.
#define B_   32
#define Q_   16
#define F_   4096
#define E_   256
#define NL_  8
#define FT   64     // feature rows per chunk
#define NTB  16     // row-tiles per batch (256 rows each)
#define CH   4      // chunks per tile (NTB*CH*FT == F_)
#define TPB  512    // 8 waves

typedef __attribute__((ext_vector_type(8))) __bf16 bf16x8_t;
typedef __attribute__((ext_vector_type(4))) __bf16 bf16x4_t;
typedef __attribute__((ext_vector_type(4))) float  f32x4;

// ---- LDS swizzle for [64][256] bf16 tiles (row stride 512 B) ----
__device__ __forceinline__ int swz(int r) {
  return ((r & 7) << 4) ^ (((r >> 3) & 3) << 5);
}
__device__ __forceinline__ int xoff(int r, int c2) {  // c2 = byte offset in row [0,512)
  return r * 512 + (c2 ^ swz(r));
}
__device__ __forceinline__ unsigned short f2bf_bits(float f) {
  __bf16 h = (__bf16)f;
  return __builtin_bit_cast(unsigned short, h);
}

// ---------------- prep: coalesced tiled transposes (8 mats, all bf16) -------
__global__ __launch_bounds__(256) void prep_kernel(
    const float* __restrict__ Wf, const float* __restrict__ Wv,
    const float* __restrict__ Wq, const float* __restrict__ Wc,
    unsigned short* __restrict__ WtF, unsigned short* __restrict__ WtV,
    unsigned short* __restrict__ WqT, unsigned short* __restrict__ WcT) {
  const int blk = blockIdx.x;
  const int t = threadIdx.x;
  __shared__ float ts[64][65];
  const int mat = blk >> 4;
  const int t16 = blk & 15;
  const int k0 = (t16 >> 2) * 64, n0 = (t16 & 3) * 64;
  const float* src;
  if (mat < 2) src = Wf + mat * 65536;
  else if (mat < 4) src = Wv + (mat - 2) * 65536;
  else if (mat < 6) src = Wq + (mat - 4) * 65536;
  else src = Wc + (mat - 6) * 65536;
#pragma unroll
  for (int p = 0; p < 16; ++p) {
    int e = p * 256 + t;
    int kk = e >> 6, nn = e & 63;
    ts[nn][kk] = src[(k0 + kk) * 256 + n0 + nn];   // coalesced in nn
  }
  __syncthreads();
  unsigned short* dst;
  if (mat < 2) dst = WtF + mat * 65536;
  else if (mat < 4) dst = WtV + (mat - 2) * 65536;
  else if (mat < 6) dst = WqT + (mat - 4) * 65536;
  else dst = WcT + (mat - 6) * 65536;
#pragma unroll
  for (int p = 0; p < 16; ++p) {
    int e = p * 256 + t;
    int nn = e >> 6, kk = e & 63;
    dst[(n0 + nn) * 256 + k0 + kk] = f2bf_bits(ts[nn][kk]);  // coalesced in kk
  }
}

// ---------------- staging: fp32 global -> bf16 swizzled LDS -----------------
__device__ __forceinline__ void stage_full(char* Xs, const float* __restrict__ src, int tid) {
#pragma unroll
  for (int j = 0; j < 4; ++j) {
    int u = j * 512 + tid;                 // 2048 units (64 rows)
    int r = u >> 5;
    const f32x4* p = (const f32x4*)(src + (size_t)r * E_ + ((u & 31) << 3));
    f32x4 a = __builtin_nontemporal_load(p);
    f32x4 b = __builtin_nontemporal_load(p + 1);
    bf16x8_t o;
    o[0] = (__bf16)a[0]; o[1] = (__bf16)a[1]; o[2] = (__bf16)a[2]; o[3] = (__bf16)a[3];
    o[4] = (__bf16)b[0]; o[5] = (__bf16)b[1]; o[6] = (__bf16)b[2]; o[7] = (__bf16)b[3];
    *(bf16x8_t*)(Xs + xoff(r, (u & 31) << 4)) = o;
  }
}
__device__ __forceinline__ void stage_quarter(char* Xs, const float* __restrict__ src, int t4) {
#pragma unroll
  for (int j = 0; j < 8; ++j) {
    int u = j * 256 + t4;
    int r = u >> 5;
    const f32x4* p = (const f32x4*)(src + (size_t)r * E_ + ((u & 31) << 3));
    f32x4 a = __builtin_nontemporal_load(p);
    f32x4 b = __builtin_nontemporal_load(p + 1);
    bf16x8_t o;
    o[0] = (__bf16)a[0]; o[1] = (__bf16)a[1]; o[2] = (__bf16)a[2]; o[3] = (__bf16)a[3];
    o[4] = (__bf16)b[0]; o[5] = (__bf16)b[1]; o[6] = (__bf16)b[2]; o[7] = (__bf16)b[3];
    *(bf16x8_t*)(Xs + xoff(r, (u & 31) << 4)) = o;
  }
}

// ---- T14 register staging (issue early, write late) ------------------------
struct StageRegs { f32x4 v[8]; };   // 32 VGPRs while live

__device__ __forceinline__ void stage_issue(StageRegs& s, const float* __restrict__ src, int tid) {
#pragma unroll
  for (int j = 0; j < 4; ++j) {
    int u = j * 512 + tid;
    int r = u >> 5;
    const f32x4* p = (const f32x4*)(src + (size_t)r * E_ + ((u & 31) << 3));
    s.v[2 * j]     = __builtin_nontemporal_load(p);
    s.v[2 * j + 1] = __builtin_nontemporal_load(p + 1);
  }
}
__device__ __forceinline__ void stage_write(const StageRegs& s, char* Xs, int tid) {
#pragma unroll
  for (int j = 0; j < 4; ++j) {
    int u = j * 512 + tid;
    int r = u >> 5;
    f32x4 a = s.v[2 * j], b = s.v[2 * j + 1];
    bf16x8_t o;
    o[0] = (__bf16)a[0]; o[1] = (__bf16)a[1]; o[2] = (__bf16)a[2]; o[3] = (__bf16)a[3];
    o[4] = (__bf16)b[0]; o[5] = (__bf16)b[1]; o[6] = (__bf16)b[2]; o[7] = (__bf16)b[3];
    *(bf16x8_t*)(Xs + xoff(r, (u & 31) << 4)) = o;
  }
}

// ---- Out-of-place residual layer, rolling depth-2 weight stream. -----------
// Reads Xin (B-frags + residual), writes Xout. ONE barrier (at end).
// Wave w owns e in [w*32, w*32+32). D[e][m].
__device__ __forceinline__ void layer_pp(const char* __restrict__ Xin, char* __restrict__ Xout,
                                         const unsigned short* __restrict__ Wt,
                                         const float* __restrict__ bias, int w, int lane) {
  const int c16 = lane & 15, g = lane >> 4, kb = g << 3;
  const unsigned short* r0 = Wt + (w * 32 + c16) * E_ + kb;
  const unsigned short* r1 = Wt + (w * 32 + 16 + c16) * E_ + kb;

  f32x4 acc[2][4];
#pragma unroll
  for (int ef = 0; ef < 2; ++ef)
#pragma unroll
    for (int mf = 0; mf < 4; ++mf) acc[ef][mf] = (f32x4){0.f, 0.f, 0.f, 0.f};

  bf16x8_t wa0 = *(const bf16x8_t*)(r0);
  bf16x8_t wa1 = *(const bf16x8_t*)(r1);
#pragma unroll
  for (int ks = 0; ks < 8; ++ks) {
    bf16x8_t nx0 = wa0, nx1 = wa1;
    if (ks < 7) {
      nx0 = *(const bf16x8_t*)(r0 + (ks + 1) * 32);
      nx1 = *(const bf16x8_t*)(r1 + (ks + 1) * 32);
    }
    const int k = ks * 32 + kb;
#pragma unroll
    for (int mf = 0; mf < 4; ++mf) {
      bf16x8_t xb = *(const bf16x8_t*)(Xin + xoff(mf * 16 + c16, k << 1));
      acc[0][mf] = __builtin_amdgcn_mfma_f32_16x16x32_bf16(wa0, xb, acc[0][mf], 0, 0, 0);
      acc[1][mf] = __builtin_amdgcn_mfma_f32_16x16x32_bf16(wa1, xb, acc[1][mf], 0, 0, 0);
    }
    wa0 = nx0; wa1 = nx1;
  }
  // no pre-write barrier: writes go to Xout (disjoint buffer)
#pragma unroll
  for (int ef = 0; ef < 2; ++ef) {
    const int e0 = w * 32 + ef * 16 + (g << 2);
    const float4 b4 = *(const float4*)(bias + e0);
#pragma unroll
    for (int mf = 0; mf < 4; ++mf) {
      const int m = mf * 16 + c16;
      bf16x4_t old = *(const bf16x4_t*)(Xin + xoff(m, e0 << 1));
      bf16x4_t nw;
      nw[0] = (__bf16)(fmaxf(acc[ef][mf][0] + b4.x, 0.f) + (float)old[0]);
      nw[1] = (__bf16)(fmaxf(acc[ef][mf][1] + b4.y, 0.f) + (float)old[1]);
      nw[2] = (__bf16)(fmaxf(acc[ef][mf][2] + b4.z, 0.f) + (float)old[2]);
      nw[3] = (__bf16)(fmaxf(acc[ef][mf][3] + b4.w, 0.f) + (float)old[3]);
      *(bf16x4_t*)(Xout + xoff(m, e0 << 1)) = nw;
    }
  }
  __syncthreads();   // everyone done reading Xin / writing Xout
}

// ---- In-place layer with 2 barriers (qmap/tail, proven R15 form) -----------
__device__ __forceinline__ void layer_ip(char* __restrict__ X,
                                         const unsigned short* __restrict__ Wt,
                                         const float* __restrict__ bias, int w, int lane) {
  const int c16 = lane & 15, g = lane >> 4, kb = g << 3;
  const unsigned short* r0 = Wt + (w * 32 + c16) * E_ + kb;
  const unsigned short* r1 = Wt + (w * 32 + 16 + c16) * E_ + kb;

  f32x4 acc[2][4];
#pragma unroll
  for (int ef = 0; ef < 2; ++ef)
#pragma unroll
    for (int mf = 0; mf < 4; ++mf) acc[ef][mf] = (f32x4){0.f, 0.f, 0.f, 0.f};

  bf16x8_t wa0 = *(const bf16x8_t*)(r0);
  bf16x8_t wa1 = *(const bf16x8_t*)(r1);
#pragma unroll
  for (int ks = 0; ks < 8; ++ks) {
    bf16x8_t nx0 = wa0, nx1 = wa1;
    if (ks < 7) {
      nx0 = *(const bf16x8_t*)(r0 + (ks + 1) * 32);
      nx1 = *(const bf16x8_t*)(r1 + (ks + 1) * 32);
    }
    const int k = ks * 32 + kb;
#pragma unroll
    for (int mf = 0; mf < 4; ++mf) {
      bf16x8_t xb = *(const bf16x8_t*)(X + xoff(mf * 16 + c16, k << 1));
      acc[0][mf] = __builtin_amdgcn_mfma_f32_16x16x32_bf16(wa0, xb, acc[0][mf], 0, 0, 0);
      acc[1][mf] = __builtin_amdgcn_mfma_f32_16x16x32_bf16(wa1, xb, acc[1][mf], 0, 0, 0);
    }
    wa0 = nx0; wa1 = nx1;
  }
  __syncthreads();
#pragma unroll
  for (int ef = 0; ef < 2; ++ef) {
    const int e0 = w * 32 + ef * 16 + (g << 2);
    const float4 b4 = *(const float4*)(bias + e0);
#pragma unroll
    for (int mf = 0; mf < 4; ++mf) {
      const int m = mf * 16 + c16;
      bf16x4_t* p = (bf16x4_t*)(X + xoff(m, e0 << 1));
      bf16x4_t old = *p;
      bf16x4_t nw;
      nw[0] = (__bf16)(fmaxf(acc[ef][mf][0] + b4.x, 0.f) + (float)old[0]);
      nw[1] = (__bf16)(fmaxf(acc[ef][mf][1] + b4.y, 0.f) + (float)old[1]);
      nw[2] = (__bf16)(fmaxf(acc[ef][mf][2] + b4.z, 0.f) + (float)old[2]);
      nw[3] = (__bf16)(fmaxf(acc[ef][mf][3] + b4.w, 0.f) + (float)old[3]);
      *p = nw;
    }
  }
  __syncthreads();
}

// ---------------- q-mapper via MFMA: 512 rows = B*Q, 8 blocks ---------------
__global__ __launch_bounds__(TPB) void qmap_kernel(
    const float* __restrict__ query, const unsigned short* __restrict__ WqT,
    const float* __restrict__ bq, unsigned short* __restrict__ qmb) {
  const int blk = blockIdx.x;                 // rows [blk*64, blk*64+64)
  const int tid = threadIdx.x;
  const int lane = tid & 63, w = tid >> 6;

  __shared__ __align__(128) char X[32768];

  stage_full(X, query + (size_t)blk * 64 * E_, tid);
  __syncthreads();

  layer_ip(X, WqT, bq, w, lane);
  layer_ip(X, WqT + 65536, bq + E_, w, lane);

#pragma unroll
  for (int j = 0; j < 4; ++j) {
    int u = j * 512 + tid;
    int r = u >> 5;
    bf16x8_t v = *(const bf16x8_t*)(X + xoff(r, (u & 31) << 4));
    *(bf16x8_t*)(qmb + (size_t)(blk * 64 + r) * E_ + ((u & 31) << 3)) = v;
  }
}

// ---------------- fused pass: F->f-mapper->S->Wl ; V->v-mapper->PV ----------
__global__ __launch_bounds__(TPB) void fused_kernel(
    const float* __restrict__ features, const float* __restrict__ values,
    const float* __restrict__ amask, const float* __restrict__ ftw,
    const unsigned short* __restrict__ WtF, const float* __restrict__ bfb,
    const unsigned short* __restrict__ WtV, const float* __restrict__ bvb,
    const unsigned short* __restrict__ qmb, float* __restrict__ partials) {
  const int bid0 = blockIdx.x;
  const int bid = (bid0 & 7) * 64 + (bid0 >> 3);   // XCD swizzle (512 % 8 == 0)
  const int b = bid >> 4, tb = bid & 15;
  const int tid = threadIdx.x;
  const int lane = tid & 63, w = tid >> 6;
  const int c16 = lane & 15, g = lane >> 4, kb = g << 3;

  __shared__ __align__(128) char X0[32768];
  __shared__ __align__(128) char X1[32768];
  __shared__ __align__(16) unsigned short Wl[Q_][FT + 8];

  const float* srcF = features + (size_t)(b * F_ + tb * CH * FT) * E_;
  const float* srcV = values   + (size_t)(b * F_ + tb * CH * FT) * E_;

  f32x4 pacc[2];
  pacc[0] = (f32x4){0.f, 0.f, 0.f, 0.f};
  pacc[1] = (f32x4){0.f, 0.f, 0.f, 0.f};

  stage_full(X0, srcF, tid);
  __syncthreads();                                 // X0 = F_0

  for (int c = 0; c < CH; ++c) {
    const int f0 = (tb * CH + c) * FT;

    // ---- f-mapper: X0 -> X1 -> X0 (Fm in X0); 1 barrier each ----
    layer_pp(X0, X1, WtF, bfb, w, lane);
    layer_pp(X1, X0, WtF + 65536, bfb + E_, w, lane);

    // ---- waves 0-3: S = qm @ Fm^T -> Wl ; waves 4-7: stage V_c -> X1 ----
    if (w < 4) {
      f32x4 sv = (f32x4){0.f, 0.f, 0.f, 0.f};
      const int fl = w * 16 + c16;
      const unsigned short* qbase = qmb + (size_t)(b * Q_ + c16) * E_ + kb;
#pragma unroll
      for (int ks = 0; ks < 8; ++ks) {
        bf16x8_t qa = *(const bf16x8_t*)(qbase + ks * 32);
        bf16x8_t xb = *(const bf16x8_t*)(X0 + xoff(fl, (ks * 32 + kb) << 1));
        sv = __builtin_amdgcn_mfma_f32_16x16x32_bf16(qa, xb, sv, 0, 0, 0);
      }
      const int fg = f0 + fl;
      const float lw = ftw[b * F_ + fg] * amask[b * F_ + fg];
#pragma unroll
      for (int r = 0; r < 4; ++r) {
        float sg = 1.f / (1.f + __expf(-sv[r]));
        Wl[g * 4 + r][fl] = f2bf_bits(sg * lw);
      }
    } else {
      stage_quarter(X1, srcV + (size_t)c * FT * E_, tid - 256);
    }
    __syncthreads();                               // X1 = V tile, Wl ready

    // ---- v-mapper: X1 -> X0 -> X1 (Vm in X1) ----
    layer_pp(X1, X0, WtV, bvb, w, lane);
    layer_pp(X0, X1, WtV + 65536, bvb + E_, w, lane);

    // ---- T14: issue next F loads; PV; write F -> X0 ----
    StageRegs s;
    if (c + 1 < CH) stage_issue(s, srcF + (size_t)(c + 1) * FT * E_, tid);

#pragma unroll
    for (int ks = 0; ks < FT / 32; ++ks) {
      bf16x8_t a = *(const bf16x8_t*)&Wl[c16][ks * 32 + kb];
#pragma unroll
      for (int nf = 0; nf < 2; ++nf) {
        const int e = w * 32 + nf * 16 + c16;
        bf16x8_t bb;
#pragma unroll
        for (int i = 0; i < 8; ++i) {
          const int f = ks * 32 + kb + i;
          bb[i] = *(const __bf16*)(X1 + xoff(f, e << 1));
        }
        pacc[nf] = __builtin_amdgcn_mfma_f32_16x16x32_bf16(a, bb, pacc[nf], 0, 0, 0);
      }
    }
    if (c + 1 < CH) stage_write(s, X0, tid);       // X0 free (vL2 read it, done)
    __syncthreads();                               // X0 = next F; X1/Wl free
  }

  // ---- write pooled partials [b][tb][q][e]; D[q][e]: q = g*4+r ----
#pragma unroll
  for (int nf = 0; nf < 2; ++nf) {
    const int e = w * 32 + nf * 16 + c16;
#pragma unroll
    for (int r = 0; r < 4; ++r) {
      const int q = g * 4 + r;
      partials[(((size_t)b * NTB + tb) * Q_ + q) * E_ + e] = pacc[nf][r];
    }
  }
}

// ---------------- tail: reduce + c-mapper (MFMA) + output projection --------
__global__ __launch_bounds__(TPB) void tail_kernel(
    const float* __restrict__ partials, const unsigned short* __restrict__ WcT,
    const float* __restrict__ bc, const float* __restrict__ Wout,
    const float* __restrict__ bout, float* __restrict__ out) {
  const int blk = blockIdx.x;                 // rows [blk*64, blk*64+64) of B*Q
  const int tid = threadIdx.x;
  const int lane = tid & 63, w = tid >> 6;

  __shared__ __align__(128) char X[32768];

  // ---- parallel reduce partials -> bf16 swizzled tile ----
#pragma unroll
  for (int j = 0; j < 4; ++j) {
    int u = j * 512 + tid;
    int rl = u >> 5;
    int R = blk * 64 + rl;
    int b = R >> 4, q = R & 15;
    int e0 = (u & 31) << 3;
    f32x4 s0 = (f32x4){0.f, 0.f, 0.f, 0.f};
    f32x4 s1 = (f32x4){0.f, 0.f, 0.f, 0.f};
#pragma unroll
    for (int tb = 0; tb < NTB; ++tb) {
      const f32x4* p = (const f32x4*)(partials + (((size_t)(b * NTB + tb)) * Q_ + q) * E_ + e0);
      s0 += p[0];
      s1 += p[1];
    }
    bf16x8_t o;
    o[0] = (__bf16)s0[0]; o[1] = (__bf16)s0[1]; o[2] = (__bf16)s0[2]; o[3] = (__bf16)s0[3];
    o[4] = (__bf16)s1[0]; o[5] = (__bf16)s1[1]; o[6] = (__bf16)s1[2]; o[7] = (__bf16)s1[3];
    *(bf16x8_t*)(X + xoff(rl, e0 << 1)) = o;
  }
  __syncthreads();

  layer_ip(X, WcT, bc, w, lane);
  layer_ip(X, WcT + 65536, bc + E_, w, lane);

  // ---- out-proj: thread -> (row rl = tid>>3, label n = tid&7) ----
  {
    const int rl = tid >> 3, n = tid & 7;
    const int R = blk * 64 + rl;
    float sum = bout[n];
#pragma unroll
    for (int k0 = 0; k0 < E_; k0 += 8) {
      bf16x8_t h8 = *(const bf16x8_t*)(X + xoff(rl, k0 << 1));
#pragma unroll
      for (int i = 0; i < 8; ++i)
        sum += (float)h8[i] * Wout[(k0 + i) * NL_ + n];
    }
    out[R * NL_ + n] = sum;
  }
}

// ---------------- launch -----------------------------------------------------
extern "C" void kernel_launch(void* const* d_in, const int* in_sizes, int n_in,
                              void* d_out, int out_size, void* d_ws, size_t ws_size,
                              hipStream_t stream) {
  (void)in_sizes; (void)n_in; (void)out_size; (void)ws_size;
  const float* query    = (const float*)d_in[0];
  const float* features = (const float*)d_in[1];
  const float* values   = (const float*)d_in[2];
  const float* amask    = (const float*)d_in[3];
  const float* ftw      = (const float*)d_in[4];
  const float* Wq       = (const float*)d_in[5];
  const float* bq       = (const float*)d_in[6];
  const float* Wf       = (const float*)d_in[7];
  const float* bfb      = (const float*)d_in[8];
  const float* Wv       = (const float*)d_in[9];
  const float* bvb      = (const float*)d_in[10];
  const float* Wc       = (const float*)d_in[11];
  const float* bcb      = (const float*)d_in[12];
  const float* Wout     = (const float*)d_in[13];
  const float* bout     = (const float*)d_in[14];
  float* out = (float*)d_out;

  char* ws = (char*)d_ws;
  unsigned short* WtF = (unsigned short*)(ws);             // 256 KB
  unsigned short* WtV = (unsigned short*)(ws + 262144);    // 256 KB
  unsigned short* WqT = (unsigned short*)(ws + 524288);    // 256 KB
  unsigned short* WcT = (unsigned short*)(ws + 786432);    // 256 KB
  unsigned short* qmb = (unsigned short*)(ws + 1048576);   // 256 KB
  float* partials     = (float*)(ws + 1310720);            // 8.4 MB

  prep_kernel<<<128, 256, 0, stream>>>(Wf, Wv, Wq, Wc, WtF, WtV, WqT, WcT);
  qmap_kernel<<<(B_ * Q_) / 64, TPB, 0, stream>>>(query, WqT, bq, qmb);
  fused_kernel<<<B_ * NTB, TPB, 0, stream>>>(features, values, amask, ftw,
                                             WtF, bfb, WtV, bvb, qmb, partials);
  tail_kernel<<<(B_ * Q_) / 64, TPB, 0, stream>>>(partials, WcT, bcb, Wout, bout, out);
}

// Round 20
// 315.885 us; speedup vs baseline: 1.1699x; 1.1699x over previous
//
#include <hip/hip_runtime.h>
#include <hip/hip_bf16.h>

// B=32, Q=16, F=4096, E=256, NL=8, L=2 residual layers per mapper.
#define B_   32
#define Q_   16
#define F_   4096
#define E_   256
#define NL_  8
#define FT   64     // feature rows per chunk
#define NTB  16     // row-tiles per batch (256 rows each)
#define CH   4      // chunks per tile (NTB*CH*FT == F_)
#define TPB  512    // 8 waves

typedef __attribute__((ext_vector_type(8))) __bf16 bf16x8_t;
typedef __attribute__((ext_vector_type(4))) __bf16 bf16x4_t;
typedef __attribute__((ext_vector_type(4))) float  f32x4;

// ---- LDS swizzle for [64][256] bf16 tiles (row stride 512 B) ----
__device__ __forceinline__ int swz(int r) {
  return ((r & 7) << 4) ^ (((r >> 3) & 3) << 5);
}
__device__ __forceinline__ int xoff(int r, int c2) {  // c2 = byte offset in row [0,512)
  return r * 512 + (c2 ^ swz(r));
}
__device__ __forceinline__ unsigned short f2bf_bits(float f) {
  __bf16 h = (__bf16)f;
  return __builtin_bit_cast(unsigned short, h);
}

// ---------------- prep: coalesced tiled transposes (8 mats, all bf16) -------
__global__ __launch_bounds__(256) void prep_kernel(
    const float* __restrict__ Wf, const float* __restrict__ Wv,
    const float* __restrict__ Wq, const float* __restrict__ Wc,
    unsigned short* __restrict__ WtF, unsigned short* __restrict__ WtV,
    unsigned short* __restrict__ WqT, unsigned short* __restrict__ WcT) {
  const int blk = blockIdx.x;
  const int t = threadIdx.x;
  __shared__ float ts[64][65];
  const int mat = blk >> 4;
  const int t16 = blk & 15;
  const int k0 = (t16 >> 2) * 64, n0 = (t16 & 3) * 64;
  const float* src;
  if (mat < 2) src = Wf + mat * 65536;
  else if (mat < 4) src = Wv + (mat - 2) * 65536;
  else if (mat < 6) src = Wq + (mat - 4) * 65536;
  else src = Wc + (mat - 6) * 65536;
#pragma unroll
  for (int p = 0; p < 16; ++p) {
    int e = p * 256 + t;
    int kk = e >> 6, nn = e & 63;
    ts[nn][kk] = src[(k0 + kk) * 256 + n0 + nn];   // coalesced in nn
  }
  __syncthreads();
  unsigned short* dst;
  if (mat < 2) dst = WtF + mat * 65536;
  else if (mat < 4) dst = WtV + (mat - 2) * 65536;
  else if (mat < 6) dst = WqT + (mat - 4) * 65536;
  else dst = WcT + (mat - 6) * 65536;
#pragma unroll
  for (int p = 0; p < 16; ++p) {
    int e = p * 256 + t;
    int nn = e >> 6, kk = e & 63;
    dst[(n0 + nn) * 256 + k0 + kk] = f2bf_bits(ts[nn][kk]);  // coalesced in kk
  }
}

// ---------------- staging: fp32 global -> bf16 swizzled LDS (flow-through) ---
__device__ __forceinline__ void stage_full(char* Xs, const float* __restrict__ src, int tid) {
#pragma unroll
  for (int j = 0; j < 4; ++j) {
    int u = j * 512 + tid;                 // 2048 units (64 rows)
    int r = u >> 5;
    const f32x4* p = (const f32x4*)(src + (size_t)r * E_ + ((u & 31) << 3));
    f32x4 a = __builtin_nontemporal_load(p);
    f32x4 b = __builtin_nontemporal_load(p + 1);
    bf16x8_t o;
    o[0] = (__bf16)a[0]; o[1] = (__bf16)a[1]; o[2] = (__bf16)a[2]; o[3] = (__bf16)a[3];
    o[4] = (__bf16)b[0]; o[5] = (__bf16)b[1]; o[6] = (__bf16)b[2]; o[7] = (__bf16)b[3];
    *(bf16x8_t*)(Xs + xoff(r, (u & 31) << 4)) = o;
  }
}
__device__ __forceinline__ void stage_quarter(char* Xs, const float* __restrict__ src, int t4) {
#pragma unroll
  for (int j = 0; j < 8; ++j) {
    int u = j * 256 + t4;
    int r = u >> 5;
    const f32x4* p = (const f32x4*)(src + (size_t)r * E_ + ((u & 31) << 3));
    f32x4 a = __builtin_nontemporal_load(p);
    f32x4 b = __builtin_nontemporal_load(p + 1);
    bf16x8_t o;
    o[0] = (__bf16)a[0]; o[1] = (__bf16)a[1]; o[2] = (__bf16)a[2]; o[3] = (__bf16)a[3];
    o[4] = (__bf16)b[0]; o[5] = (__bf16)b[1]; o[6] = (__bf16)b[2]; o[7] = (__bf16)b[3];
    *(bf16x8_t*)(Xs + xoff(r, (u & 31) << 4)) = o;
  }
}

// ---- Out-of-place residual layer, rolling depth-2 weight stream. -----------
// Reads Xin (B-frags + residual), writes Xout. ONE barrier (at end).
// Wave w owns e in [w*32, w*32+32). D[e][m].
__device__ __forceinline__ void layer_pp(const char* __restrict__ Xin, char* __restrict__ Xout,
                                         const unsigned short* __restrict__ Wt,
                                         const float* __restrict__ bias, int w, int lane) {
  const int c16 = lane & 15, g = lane >> 4, kb = g << 3;
  const unsigned short* r0 = Wt + (w * 32 + c16) * E_ + kb;
  const unsigned short* r1 = Wt + (w * 32 + 16 + c16) * E_ + kb;

  f32x4 acc[2][4];
#pragma unroll
  for (int ef = 0; ef < 2; ++ef)
#pragma unroll
    for (int mf = 0; mf < 4; ++mf) acc[ef][mf] = (f32x4){0.f, 0.f, 0.f, 0.f};

  bf16x8_t wa0 = *(const bf16x8_t*)(r0);
  bf16x8_t wa1 = *(const bf16x8_t*)(r1);
#pragma unroll
  for (int ks = 0; ks < 8; ++ks) {
    bf16x8_t nx0 = wa0, nx1 = wa1;
    if (ks < 7) {
      nx0 = *(const bf16x8_t*)(r0 + (ks + 1) * 32);
      nx1 = *(const bf16x8_t*)(r1 + (ks + 1) * 32);
    }
    const int k = ks * 32 + kb;
#pragma unroll
    for (int mf = 0; mf < 4; ++mf) {
      bf16x8_t xb = *(const bf16x8_t*)(Xin + xoff(mf * 16 + c16, k << 1));
      acc[0][mf] = __builtin_amdgcn_mfma_f32_16x16x32_bf16(wa0, xb, acc[0][mf], 0, 0, 0);
      acc[1][mf] = __builtin_amdgcn_mfma_f32_16x16x32_bf16(wa1, xb, acc[1][mf], 0, 0, 0);
    }
    wa0 = nx0; wa1 = nx1;
  }
  // no pre-write barrier: writes go to Xout (disjoint buffer)
#pragma unroll
  for (int ef = 0; ef < 2; ++ef) {
    const int e0 = w * 32 + ef * 16 + (g << 2);
    const float4 b4 = *(const float4*)(bias + e0);
#pragma unroll
    for (int mf = 0; mf < 4; ++mf) {
      const int m = mf * 16 + c16;
      bf16x4_t old = *(const bf16x4_t*)(Xin + xoff(m, e0 << 1));
      bf16x4_t nw;
      nw[0] = (__bf16)(fmaxf(acc[ef][mf][0] + b4.x, 0.f) + (float)old[0]);
      nw[1] = (__bf16)(fmaxf(acc[ef][mf][1] + b4.y, 0.f) + (float)old[1]);
      nw[2] = (__bf16)(fmaxf(acc[ef][mf][2] + b4.z, 0.f) + (float)old[2]);
      nw[3] = (__bf16)(fmaxf(acc[ef][mf][3] + b4.w, 0.f) + (float)old[3]);
      *(bf16x4_t*)(Xout + xoff(m, e0 << 1)) = nw;
    }
  }
  __syncthreads();   // everyone done reading Xin / writing Xout
}

// ---- In-place layer with 2 barriers (qmap/tail, proven R15 form) -----------
__device__ __forceinline__ void layer_ip(char* __restrict__ X,
                                         const unsigned short* __restrict__ Wt,
                                         const float* __restrict__ bias, int w, int lane) {
  const int c16 = lane & 15, g = lane >> 4, kb = g << 3;
  const unsigned short* r0 = Wt + (w * 32 + c16) * E_ + kb;
  const unsigned short* r1 = Wt + (w * 32 + 16 + c16) * E_ + kb;

  f32x4 acc[2][4];
#pragma unroll
  for (int ef = 0; ef < 2; ++ef)
#pragma unroll
    for (int mf = 0; mf < 4; ++mf) acc[ef][mf] = (f32x4){0.f, 0.f, 0.f, 0.f};

  bf16x8_t wa0 = *(const bf16x8_t*)(r0);
  bf16x8_t wa1 = *(const bf16x8_t*)(r1);
#pragma unroll
  for (int ks = 0; ks < 8; ++ks) {
    bf16x8_t nx0 = wa0, nx1 = wa1;
    if (ks < 7) {
      nx0 = *(const bf16x8_t*)(r0 + (ks + 1) * 32);
      nx1 = *(const bf16x8_t*)(r1 + (ks + 1) * 32);
    }
    const int k = ks * 32 + kb;
#pragma unroll
    for (int mf = 0; mf < 4; ++mf) {
      bf16x8_t xb = *(const bf16x8_t*)(X + xoff(mf * 16 + c16, k << 1));
      acc[0][mf] = __builtin_amdgcn_mfma_f32_16x16x32_bf16(wa0, xb, acc[0][mf], 0, 0, 0);
      acc[1][mf] = __builtin_amdgcn_mfma_f32_16x16x32_bf16(wa1, xb, acc[1][mf], 0, 0, 0);
    }
    wa0 = nx0; wa1 = nx1;
  }
  __syncthreads();
#pragma unroll
  for (int ef = 0; ef < 2; ++ef) {
    const int e0 = w * 32 + ef * 16 + (g << 2);
    const float4 b4 = *(const float4*)(bias + e0);
#pragma unroll
    for (int mf = 0; mf < 4; ++mf) {
      const int m = mf * 16 + c16;
      bf16x4_t* p = (bf16x4_t*)(X + xoff(m, e0 << 1));
      bf16x4_t old = *p;
      bf16x4_t nw;
      nw[0] = (__bf16)(fmaxf(acc[ef][mf][0] + b4.x, 0.f) + (float)old[0]);
      nw[1] = (__bf16)(fmaxf(acc[ef][mf][1] + b4.y, 0.f) + (float)old[1]);
      nw[2] = (__bf16)(fmaxf(acc[ef][mf][2] + b4.z, 0.f) + (float)old[2]);
      nw[3] = (__bf16)(fmaxf(acc[ef][mf][3] + b4.w, 0.f) + (float)old[3]);
      *p = nw;
    }
  }
  __syncthreads();
}

// ---------------- q-mapper via MFMA: 512 rows = B*Q, 8 blocks ---------------
__global__ __launch_bounds__(TPB) void qmap_kernel(
    const float* __restrict__ query, const unsigned short* __restrict__ WqT,
    const float* __restrict__ bq, unsigned short* __restrict__ qmb) {
  const int blk = blockIdx.x;                 // rows [blk*64, blk*64+64)
  const int tid = threadIdx.x;
  const int lane = tid & 63, w = tid >> 6;

  __shared__ __align__(128) char X[32768];

  stage_full(X, query + (size_t)blk * 64 * E_, tid);
  __syncthreads();

  layer_ip(X, WqT, bq, w, lane);
  layer_ip(X, WqT + 65536, bq + E_, w, lane);

#pragma unroll
  for (int j = 0; j < 4; ++j) {
    int u = j * 512 + tid;
    int r = u >> 5;
    bf16x8_t v = *(const bf16x8_t*)(X + xoff(r, (u & 31) << 4));
    *(bf16x8_t*)(qmb + (size_t)(blk * 64 + r) * E_ + ((u & 31) << 3)) = v;
  }
}

// ---------------- fused pass: F->f-mapper->S->Wl ; V->v-mapper->PV ----------
__global__ __launch_bounds__(TPB) void fused_kernel(
    const float* __restrict__ features, const float* __restrict__ values,
    const float* __restrict__ amask, const float* __restrict__ ftw,
    const unsigned short* __restrict__ WtF, const float* __restrict__ bfb,
    const unsigned short* __restrict__ WtV, const float* __restrict__ bvb,
    const unsigned short* __restrict__ qmb, float* __restrict__ partials) {
  const int bid0 = blockIdx.x;
  const int bid = (bid0 & 7) * 64 + (bid0 >> 3);   // XCD swizzle (512 % 8 == 0)
  const int b = bid >> 4, tb = bid & 15;
  const int tid = threadIdx.x;
  const int lane = tid & 63, w = tid >> 6;
  const int c16 = lane & 15, g = lane >> 4, kb = g << 3;

  __shared__ __align__(128) char X0[32768];
  __shared__ __align__(128) char X1[32768];
  __shared__ __align__(16) unsigned short Wl[Q_][FT + 8];

  const float* srcF = features + (size_t)(b * F_ + tb * CH * FT) * E_;
  const float* srcV = values   + (size_t)(b * F_ + tb * CH * FT) * E_;

  f32x4 pacc[2];
  pacc[0] = (f32x4){0.f, 0.f, 0.f, 0.f};
  pacc[1] = (f32x4){0.f, 0.f, 0.f, 0.f};

  stage_full(X0, srcF, tid);
  __syncthreads();                                 // X0 = F_0

  for (int c = 0; c < CH; ++c) {
    const int f0 = (tb * CH + c) * FT;

    // ---- f-mapper: X0 -> X1 -> X0 (Fm in X0); 1 barrier each ----
    layer_pp(X0, X1, WtF, bfb, w, lane);
    layer_pp(X1, X0, WtF + 65536, bfb + E_, w, lane);

    // ---- waves 0-3: S = qm @ Fm^T -> Wl ; waves 4-7: stage V_c -> X1 ----
    if (w < 4) {
      f32x4 sv = (f32x4){0.f, 0.f, 0.f, 0.f};
      const int fl = w * 16 + c16;
      const unsigned short* qbase = qmb + (size_t)(b * Q_ + c16) * E_ + kb;
#pragma unroll
      for (int ks = 0; ks < 8; ++ks) {
        bf16x8_t qa = *(const bf16x8_t*)(qbase + ks * 32);
        bf16x8_t xb = *(const bf16x8_t*)(X0 + xoff(fl, (ks * 32 + kb) << 1));
        sv = __builtin_amdgcn_mfma_f32_16x16x32_bf16(qa, xb, sv, 0, 0, 0);
      }
      const int fg = f0 + fl;
      const float lw = ftw[b * F_ + fg] * amask[b * F_ + fg];
#pragma unroll
      for (int r = 0; r < 4; ++r) {
        float sg = 1.f / (1.f + __expf(-sv[r]));
        Wl[g * 4 + r][fl] = f2bf_bits(sg * lw);
      }
    } else {
      stage_quarter(X1, srcV + (size_t)c * FT * E_, tid - 256);
    }
    __syncthreads();                               // X1 = V tile, Wl ready

    // ---- v-mapper: X1 -> X0 -> X1 (Vm in X1) ----
    layer_pp(X1, X0, WtV, bvb, w, lane);
    layer_pp(X0, X1, WtV + 65536, bvb + E_, w, lane);

    // ---- stage next F -> X0 (X0 dead after vL2 barrier), then PV ----
    // Flow-through staging: issued before PV so other waves' PV hides the
    // HBM latency; no registers held across phases (the R19 spill source).
    if (c + 1 < CH) stage_full(X0, srcF + (size_t)(c + 1) * FT * E_, tid);

#pragma unroll
    for (int ks = 0; ks < FT / 32; ++ks) {
      bf16x8_t a = *(const bf16x8_t*)&Wl[c16][ks * 32 + kb];
#pragma unroll
      for (int nf = 0; nf < 2; ++nf) {
        const int e = w * 32 + nf * 16 + c16;
        bf16x8_t bb;
#pragma unroll
        for (int i = 0; i < 8; ++i) {
          const int f = ks * 32 + kb + i;
          bb[i] = *(const __bf16*)(X1 + xoff(f, e << 1));
        }
        pacc[nf] = __builtin_amdgcn_mfma_f32_16x16x32_bf16(a, bb, pacc[nf], 0, 0, 0);
      }
    }
    __syncthreads();                               // X0 = next F; X1/Wl free
  }

  // ---- write pooled partials [b][tb][q][e]; D[q][e]: q = g*4+r ----
#pragma unroll
  for (int nf = 0; nf < 2; ++nf) {
    const int e = w * 32 + nf * 16 + c16;
#pragma unroll
    for (int r = 0; r < 4; ++r) {
      const int q = g * 4 + r;
      partials[(((size_t)b * NTB + tb) * Q_ + q) * E_ + e] = pacc[nf][r];
    }
  }
}

// ---------------- tail: reduce + c-mapper (MFMA) + output projection --------
__global__ __launch_bounds__(TPB) void tail_kernel(
    const float* __restrict__ partials, const unsigned short* __restrict__ WcT,
    const float* __restrict__ bc, const float* __restrict__ Wout,
    const float* __restrict__ bout, float* __restrict__ out) {
  const int blk = blockIdx.x;                 // rows [blk*64, blk*64+64) of B*Q
  const int tid = threadIdx.x;
  const int lane = tid & 63, w = tid >> 6;

  __shared__ __align__(128) char X[32768];

  // ---- parallel reduce partials -> bf16 swizzled tile ----
#pragma unroll
  for (int j = 0; j < 4; ++j) {
    int u = j * 512 + tid;
    int rl = u >> 5;
    int R = blk * 64 + rl;
    int b = R >> 4, q = R & 15;
    int e0 = (u & 31) << 3;
    f32x4 s0 = (f32x4){0.f, 0.f, 0.f, 0.f};
    f32x4 s1 = (f32x4){0.f, 0.f, 0.f, 0.f};
#pragma unroll
    for (int tb = 0; tb < NTB; ++tb) {
      const f32x4* p = (const f32x4*)(partials + (((size_t)(b * NTB + tb)) * Q_ + q) * E_ + e0);
      s0 += p[0];
      s1 += p[1];
    }
    bf16x8_t o;
    o[0] = (__bf16)s0[0]; o[1] = (__bf16)s0[1]; o[2] = (__bf16)s0[2]; o[3] = (__bf16)s0[3];
    o[4] = (__bf16)s1[0]; o[5] = (__bf16)s1[1]; o[6] = (__bf16)s1[2]; o[7] = (__bf16)s1[3];
    *(bf16x8_t*)(X + xoff(rl, e0 << 1)) = o;
  }
  __syncthreads();

  layer_ip(X, WcT, bc, w, lane);
  layer_ip(X, WcT + 65536, bc + E_, w, lane);

  // ---- out-proj: thread -> (row rl = tid>>3, label n = tid&7) ----
  {
    const int rl = tid >> 3, n = tid & 7;
    const int R = blk * 64 + rl;
    float sum = bout[n];
#pragma unroll
    for (int k0 = 0; k0 < E_; k0 += 8) {
      bf16x8_t h8 = *(const bf16x8_t*)(X + xoff(rl, k0 << 1));
#pragma unroll
      for (int i = 0; i < 8; ++i)
        sum += (float)h8[i] * Wout[(k0 + i) * NL_ + n];
    }
    out[R * NL_ + n] = sum;
  }
}

// ---------------- launch -----------------------------------------------------
extern "C" void kernel_launch(void* const* d_in, const int* in_sizes, int n_in,
                              void* d_out, int out_size, void* d_ws, size_t ws_size,
                              hipStream_t stream) {
  (void)in_sizes; (void)n_in; (void)out_size; (void)ws_size;
  const float* query    = (const float*)d_in[0];
  const float* features = (const float*)d_in[1];
  const float* values   = (const float*)d_in[2];
  const float* amask    = (const float*)d_in[3];
  const float* ftw      = (const float*)d_in[4];
  const float* Wq       = (const float*)d_in[5];
  const float* bq       = (const float*)d_in[6];
  const float* Wf       = (const float*)d_in[7];
  const float* bfb      = (const float*)d_in[8];
  const float* Wv       = (const float*)d_in[9];
  const float* bvb      = (const float*)d_in[10];
  const float* Wc       = (const float*)d_in[11];
  const float* bcb      = (const float*)d_in[12];
  const float* Wout     = (const float*)d_in[13];
  const float* bout     = (const float*)d_in[14];
  float* out = (float*)d_out;

  char* ws = (char*)d_ws;
  unsigned short* WtF = (unsigned short*)(ws);             // 256 KB
  unsigned short* WtV = (unsigned short*)(ws + 262144);    // 256 KB
  unsigned short* WqT = (unsigned short*)(ws + 524288);    // 256 KB
  unsigned short* WcT = (unsigned short*)(ws + 786432);    // 256 KB
  unsigned short* qmb = (unsigned short*)(ws + 1048576);   // 256 KB
  float* partials     = (float*)(ws + 1310720);            // 8.4 MB

  prep_kernel<<<128, 256, 0, stream>>>(Wf, Wv, Wq, Wc, WtF, WtV, WqT, WcT);
  qmap_kernel<<<(B_ * Q_) / 64, TPB, 0, stream>>>(query, WqT, bq, qmb);
  fused_kernel<<<B_ * NTB, TPB, 0, stream>>>(features, values, amask, ftw,
                                             WtF, bfb, WtV, bvb, qmb, partials);
  tail_kernel<<<(B_ * Q_) / 64, TPB, 0, stream>>>(partials, WcT, bcb, Wout, bout, out);
}

// Round 21
// 232.764 us; speedup vs baseline: 1.5877x; 1.3571x over previous
//
#include <hip/hip_runtime.h>
#include <hip/hip_bf16.h>

// B=32, Q=16, F=4096, E=256, NL=8, L=2 residual layers per mapper.
#define B_   32
#define Q_   16
#define F_   4096
#define E_   256
#define NL_  8
#define FT   64     // feature rows per chunk
#define NTB  16     // row-tiles per batch (256 rows each)
#define CH   4      // chunks per tile (NTB*CH*FT == F_)
#define TPB  512    // 8 waves

typedef __attribute__((ext_vector_type(8))) __bf16 bf16x8_t;
typedef __attribute__((ext_vector_type(4))) __bf16 bf16x4_t;
typedef __attribute__((ext_vector_type(4))) float  f32x4;

// ---- LDS swizzle for [64][256] bf16 tiles (row stride 512 B) ----
__device__ __forceinline__ int swz(int r) {
  return ((r & 7) << 4) ^ (((r >> 3) & 3) << 5);
}
__device__ __forceinline__ int xoff(int r, int c2) {  // c2 = byte offset in row [0,512)
  return r * 512 + (c2 ^ swz(r));
}
__device__ __forceinline__ unsigned short f2bf_bits(float f) {
  __bf16 h = (__bf16)f;
  return __builtin_bit_cast(unsigned short, h);
}

// ---------------- prep: coalesced tiled transposes (8 mats, all bf16) -------
__global__ __launch_bounds__(256) void prep_kernel(
    const float* __restrict__ Wf, const float* __restrict__ Wv,
    const float* __restrict__ Wq, const float* __restrict__ Wc,
    unsigned short* __restrict__ WtF, unsigned short* __restrict__ WtV,
    unsigned short* __restrict__ WqT, unsigned short* __restrict__ WcT) {
  const int blk = blockIdx.x;
  const int t = threadIdx.x;
  __shared__ float ts[64][65];
  const int mat = blk >> 4;
  const int t16 = blk & 15;
  const int k0 = (t16 >> 2) * 64, n0 = (t16 & 3) * 64;
  const float* src;
  if (mat < 2) src = Wf + mat * 65536;
  else if (mat < 4) src = Wv + (mat - 2) * 65536;
  else if (mat < 6) src = Wq + (mat - 4) * 65536;
  else src = Wc + (mat - 6) * 65536;
#pragma unroll
  for (int p = 0; p < 16; ++p) {
    int e = p * 256 + t;
    int kk = e >> 6, nn = e & 63;
    ts[nn][kk] = src[(k0 + kk) * 256 + n0 + nn];   // coalesced in nn
  }
  __syncthreads();
  unsigned short* dst;
  if (mat < 2) dst = WtF + mat * 65536;
  else if (mat < 4) dst = WtV + (mat - 2) * 65536;
  else if (mat < 6) dst = WqT + (mat - 4) * 65536;
  else dst = WcT + (mat - 6) * 65536;
#pragma unroll
  for (int p = 0; p < 16; ++p) {
    int e = p * 256 + t;
    int nn = e >> 6, kk = e & 63;
    dst[(n0 + nn) * 256 + k0 + kk] = f2bf_bits(ts[nn][kk]);  // coalesced in kk
  }
}

// ---------------- staging: fp32 global -> bf16 swizzled LDS (immediate) -----
__device__ __forceinline__ void cvt_store(char* Xs, int r, int cb, const float* __restrict__ p) {
  const f32x4* s4 = (const f32x4*)p;
  f32x4 a = __builtin_nontemporal_load(s4);
  f32x4 b = __builtin_nontemporal_load(s4 + 1);
  bf16x8_t o;
  o[0] = (__bf16)a[0]; o[1] = (__bf16)a[1]; o[2] = (__bf16)a[2]; o[3] = (__bf16)a[3];
  o[4] = (__bf16)b[0]; o[5] = (__bf16)b[1]; o[6] = (__bf16)b[2]; o[7] = (__bf16)b[3];
  *(bf16x8_t*)(Xs + xoff(r, cb)) = o;
}
__device__ __forceinline__ void stage_tile(char* Xs, const float* __restrict__ src, int tid) {
#pragma unroll
  for (int j = 0; j < 4; ++j) {
    int u = j * 512 + tid;                 // 16B-out-unit id (2048 per 64-row tile)
    int r = u >> 5;
    cvt_store(Xs, r, (u & 31) << 4, src + (size_t)r * E_ + ((u & 31) << 3));
  }
}

// ---- In-place residual layer, rolling depth-2 weight stream ----------------
// Wave w owns e in [w*32, w*32+32). D[e][m]. Two barriers: reads-done, writes-done.
__device__ __forceinline__ void layer_ip(char* __restrict__ X,
                                         const unsigned short* __restrict__ Wt,
                                         const float* __restrict__ bias, int w, int lane) {
  const int c16 = lane & 15, g = lane >> 4, kb = g << 3;
  const unsigned short* r0 = Wt + (w * 32 + c16) * E_ + kb;
  const unsigned short* r1 = Wt + (w * 32 + 16 + c16) * E_ + kb;

  f32x4 acc[2][4];
#pragma unroll
  for (int ef = 0; ef < 2; ++ef)
#pragma unroll
    for (int mf = 0; mf < 4; ++mf) acc[ef][mf] = (f32x4){0.f, 0.f, 0.f, 0.f};

  bf16x8_t wa0 = *(const bf16x8_t*)(r0);
  bf16x8_t wa1 = *(const bf16x8_t*)(r1);
#pragma unroll
  for (int ks = 0; ks < 8; ++ks) {
    bf16x8_t nx0 = wa0, nx1 = wa1;
    if (ks < 7) {                    // prefetch next k-step while MFMAs run
      nx0 = *(const bf16x8_t*)(r0 + (ks + 1) * 32);
      nx1 = *(const bf16x8_t*)(r1 + (ks + 1) * 32);
    }
    const int k = ks * 32 + kb;
#pragma unroll
    for (int mf = 0; mf < 4; ++mf) {
      bf16x8_t xb = *(const bf16x8_t*)(X + xoff(mf * 16 + c16, k << 1));
      acc[0][mf] = __builtin_amdgcn_mfma_f32_16x16x32_bf16(wa0, xb, acc[0][mf], 0, 0, 0);
      acc[1][mf] = __builtin_amdgcn_mfma_f32_16x16x32_bf16(wa1, xb, acc[1][mf], 0, 0, 0);
    }
    wa0 = nx0; wa1 = nx1;
  }
  __syncthreads();   // all waves' reads of X done before in-place writes
#pragma unroll
  for (int ef = 0; ef < 2; ++ef) {
    const int e0 = w * 32 + ef * 16 + (g << 2);
    const float4 b4 = *(const float4*)(bias + e0);
#pragma unroll
    for (int mf = 0; mf < 4; ++mf) {
      const int m = mf * 16 + c16;
      bf16x4_t* p = (bf16x4_t*)(X + xoff(m, e0 << 1));
      bf16x4_t old = *p;
      bf16x4_t nw;
      nw[0] = (__bf16)(fmaxf(acc[ef][mf][0] + b4.x, 0.f) + (float)old[0]);
      nw[1] = (__bf16)(fmaxf(acc[ef][mf][1] + b4.y, 0.f) + (float)old[1]);
      nw[2] = (__bf16)(fmaxf(acc[ef][mf][2] + b4.z, 0.f) + (float)old[2]);
      nw[3] = (__bf16)(fmaxf(acc[ef][mf][3] + b4.w, 0.f) + (float)old[3]);
      *p = nw;
    }
  }
  __syncthreads();
}

// ---------------- q-mapper via MFMA: 512 rows = B*Q, 8 blocks ---------------
__global__ __launch_bounds__(TPB) void qmap_kernel(
    const float* __restrict__ query, const unsigned short* __restrict__ WqT,
    const float* __restrict__ bq, unsigned short* __restrict__ qmb) {
  const int blk = blockIdx.x;                 // rows [blk*64, blk*64+64)
  const int tid = threadIdx.x;
  const int lane = tid & 63, w = tid >> 6;

  __shared__ __align__(128) char X[32768];

  stage_tile(X, query + (size_t)blk * 64 * E_, tid);
  __syncthreads();

  layer_ip(X, WqT, bq, w, lane);
  layer_ip(X, WqT + 65536, bq + E_, w, lane);

#pragma unroll
  for (int j = 0; j < 4; ++j) {
    int u = j * 512 + tid;
    int r = u >> 5;
    bf16x8_t v = *(const bf16x8_t*)(X + xoff(r, (u & 31) << 4));
    *(bf16x8_t*)(qmb + (size_t)(blk * 64 + r) * E_ + ((u & 31) << 3)) = v;
  }
}

// ---------------- pass A: features -> f-mapper -> S -> Ws -------------------
__global__ __launch_bounds__(TPB) void passA_kernel(
    const float* __restrict__ features,
    const float* __restrict__ amask, const float* __restrict__ ftw,
    const unsigned short* __restrict__ WtF, const float* __restrict__ bfb,
    const unsigned short* __restrict__ qmb, unsigned short* __restrict__ Wsg) {
  const int bid0 = blockIdx.x;
  const int bid = (bid0 & 7) * 64 + (bid0 >> 3);   // XCD swizzle (512 % 8 == 0)
  const int b = bid >> 4, tb = bid & 15;
  const int tid = threadIdx.x;
  const int lane = tid & 63, w = tid >> 6;
  const int c16 = lane & 15, g = lane >> 4, kb = g << 3;

  __shared__ __align__(128) char X[2][32768];   // double buffer

  const float* srcB = features + (size_t)(b * F_ + tb * CH * FT) * E_;

  stage_tile(X[0], srcB, tid);
  __syncthreads();
  int cur = 0;

  for (int c = 0; c < CH; ++c) {
    // stage next chunk into the dead buffer (immediate; TLP hides latency)
    if (c + 1 < CH) stage_tile(X[cur ^ 1], srcB + (size_t)(c + 1) * FT * E_, tid);

    layer_ip(X[cur], WtF, bfb, w, lane);             // 2 barriers inside
    layer_ip(X[cur], WtF + 65536, bfb + E_, w, lane);

    // ---- S = qm @ Fm^T (waves 0-3; wave w owns f rows [w*16, w*16+16)) ----
    if (w < 4) {
      const int f0 = (tb * CH + c) * FT;
      f32x4 sv = (f32x4){0.f, 0.f, 0.f, 0.f};
      const int fl = w * 16 + c16;
      const unsigned short* qbase = qmb + (size_t)(b * Q_ + c16) * E_ + kb;
#pragma unroll
      for (int ks = 0; ks < 8; ++ks) {
        bf16x8_t qa = *(const bf16x8_t*)(qbase + ks * 32);
        bf16x8_t xb = *(const bf16x8_t*)(X[cur] + xoff(fl, (ks * 32 + kb) << 1));
        sv = __builtin_amdgcn_mfma_f32_16x16x32_bf16(qa, xb, sv, 0, 0, 0);
      }
      const int fg = f0 + fl;
      const float lw = ftw[b * F_ + fg] * amask[b * F_ + fg];
#pragma unroll
      for (int r = 0; r < 4; ++r) {
        float sg = 1.f / (1.f + __expf(-sv[r]));
        Wsg[((size_t)(b * Q_ + g * 4 + r)) * F_ + fg] = f2bf_bits(sg * lw);
      }
    }
    __syncthreads();                       // staging + S complete
    cur ^= 1;
  }
}

// ---------------- pass B: values -> v-mapper -> PV -> partials --------------
__global__ __launch_bounds__(TPB) void passB_kernel(
    const float* __restrict__ values,
    const unsigned short* __restrict__ WtV, const float* __restrict__ bvb,
    const unsigned short* __restrict__ Wsg, float* __restrict__ partials) {
  const int bid0 = blockIdx.x;
  const int bid = (bid0 & 7) * 64 + (bid0 >> 3);
  const int b = bid >> 4, tb = bid & 15;
  const int tid = threadIdx.x;
  const int lane = tid & 63, w = tid >> 6;
  const int c16 = lane & 15, g = lane >> 4, kb = g << 3;

  __shared__ __align__(128) char X[2][32768];
  __shared__ __align__(16) unsigned short Wl[Q_][FT + 8];

  const float* srcB = values + (size_t)(b * F_ + tb * CH * FT) * E_;

  f32x4 pacc[2];
  pacc[0] = (f32x4){0.f, 0.f, 0.f, 0.f};
  pacc[1] = (f32x4){0.f, 0.f, 0.f, 0.f};

  stage_tile(X[0], srcB, tid);
  __syncthreads();
  int cur = 0;

  for (int c = 0; c < CH; ++c) {
    const int f0 = (tb * CH + c) * FT;
    if (c + 1 < CH) stage_tile(X[cur ^ 1], srcB + (size_t)(c + 1) * FT * E_, tid);

    layer_ip(X[cur], WtV, bvb, w, lane);             // 2 barriers inside

    // attn weights for this chunk (ordered before PV by layer2's barriers)
#pragma unroll
    for (int kk = 0; kk < 2; ++kk) {
      int idx = tid + kk * 512;              // 1024 = 16 q x 64 f
      int q = idx >> 6, j = idx & 63;
      Wl[q][j] = Wsg[((size_t)(b * Q_ + q)) * F_ + f0 + j];
    }

    layer_ip(X[cur], WtV + 65536, bvb + E_, w, lane);

    // ---- P += Wl[16,FT] @ Vm[FT,256]; wave w owns e in [w*32, w*32+32) ----
#pragma unroll
    for (int ks = 0; ks < FT / 32; ++ks) {
      bf16x8_t a = *(const bf16x8_t*)&Wl[c16][ks * 32 + kb];
#pragma unroll
      for (int nf = 0; nf < 2; ++nf) {
        const int e = w * 32 + nf * 16 + c16;
        bf16x8_t bb;
#pragma unroll
        for (int i = 0; i < 8; ++i) {
          const int f = ks * 32 + kb + i;
          bb[i] = *(const __bf16*)(X[cur] + xoff(f, e << 1));
        }
        pacc[nf] = __builtin_amdgcn_mfma_f32_16x16x32_bf16(a, bb, pacc[nf], 0, 0, 0);
      }
    }
    __syncthreads();                       // PV + staging complete
    cur ^= 1;
  }

  // ---- write pooled partials [b][tb][q][e]; D[q][e]: q = g*4+r ----
#pragma unroll
  for (int nf = 0; nf < 2; ++nf) {
    const int e = w * 32 + nf * 16 + c16;
#pragma unroll
    for (int r = 0; r < 4; ++r) {
      const int q = g * 4 + r;
      partials[(((size_t)b * NTB + tb) * Q_ + q) * E_ + e] = pacc[nf][r];
    }
  }
}

// ---------------- tail: reduce + c-mapper (MFMA) + output projection --------
__global__ __launch_bounds__(TPB) void tail_kernel(
    const float* __restrict__ partials, const unsigned short* __restrict__ WcT,
    const float* __restrict__ bc, const float* __restrict__ Wout,
    const float* __restrict__ bout, float* __restrict__ out) {
  const int blk = blockIdx.x;                 // rows [blk*64, blk*64+64) of B*Q
  const int tid = threadIdx.x;
  const int lane = tid & 63, w = tid >> 6;

  __shared__ __align__(128) char X[32768];

  // ---- parallel reduce partials -> bf16 swizzled tile ----
#pragma unroll
  for (int j = 0; j < 4; ++j) {
    int u = j * 512 + tid;
    int rl = u >> 5;
    int R = blk * 64 + rl;
    int b = R >> 4, q = R & 15;
    int e0 = (u & 31) << 3;
    f32x4 s0 = (f32x4){0.f, 0.f, 0.f, 0.f};
    f32x4 s1 = (f32x4){0.f, 0.f, 0.f, 0.f};
#pragma unroll
    for (int tb = 0; tb < NTB; ++tb) {
      const f32x4* p = (const f32x4*)(partials + (((size_t)(b * NTB + tb)) * Q_ + q) * E_ + e0);
      s0 += p[0];
      s1 += p[1];
    }
    bf16x8_t o;
    o[0] = (__bf16)s0[0]; o[1] = (__bf16)s0[1]; o[2] = (__bf16)s0[2]; o[3] = (__bf16)s0[3];
    o[4] = (__bf16)s1[0]; o[5] = (__bf16)s1[1]; o[6] = (__bf16)s1[2]; o[7] = (__bf16)s1[3];
    *(bf16x8_t*)(X + xoff(rl, e0 << 1)) = o;
  }
  __syncthreads();

  layer_ip(X, WcT, bc, w, lane);
  layer_ip(X, WcT + 65536, bc + E_, w, lane);

  // ---- out-proj: thread -> (row rl = tid>>3, label n = tid&7) ----
  {
    const int rl = tid >> 3, n = tid & 7;
    const int R = blk * 64 + rl;
    float sum = bout[n];
#pragma unroll
    for (int k0 = 0; k0 < E_; k0 += 8) {
      bf16x8_t h8 = *(const bf16x8_t*)(X + xoff(rl, k0 << 1));
#pragma unroll
      for (int i = 0; i < 8; ++i)
        sum += (float)h8[i] * Wout[(k0 + i) * NL_ + n];
    }
    out[R * NL_ + n] = sum;
  }
}

// ---------------- launch -----------------------------------------------------
extern "C" void kernel_launch(void* const* d_in, const int* in_sizes, int n_in,
                              void* d_out, int out_size, void* d_ws, size_t ws_size,
                              hipStream_t stream) {
  (void)in_sizes; (void)n_in; (void)out_size; (void)ws_size;
  const float* query    = (const float*)d_in[0];
  const float* features = (const float*)d_in[1];
  const float* values   = (const float*)d_in[2];
  const float* amask    = (const float*)d_in[3];
  const float* ftw      = (const float*)d_in[4];
  const float* Wq       = (const float*)d_in[5];
  const float* bq       = (const float*)d_in[6];
  const float* Wf       = (const float*)d_in[7];
  const float* bfb      = (const float*)d_in[8];
  const float* Wv       = (const float*)d_in[9];
  const float* bvb      = (const float*)d_in[10];
  const float* Wc       = (const float*)d_in[11];
  const float* bcb      = (const float*)d_in[12];
  const float* Wout     = (const float*)d_in[13];
  const float* bout     = (const float*)d_in[14];
  float* out = (float*)d_out;

  char* ws = (char*)d_ws;
  unsigned short* WtF = (unsigned short*)(ws);             // 256 KB
  unsigned short* WtV = (unsigned short*)(ws + 262144);    // 256 KB
  unsigned short* WqT = (unsigned short*)(ws + 524288);    // 256 KB
  unsigned short* WcT = (unsigned short*)(ws + 786432);    // 256 KB
  unsigned short* qmb = (unsigned short*)(ws + 1048576);   // 256 KB
  unsigned short* Wsg = (unsigned short*)(ws + 1310720);   // 4 MB
  float* partials     = (float*)(ws + 5505024);            // 8.4 MB

  prep_kernel<<<128, 256, 0, stream>>>(Wf, Wv, Wq, Wc, WtF, WtV, WqT, WcT);
  qmap_kernel<<<(B_ * Q_) / 64, TPB, 0, stream>>>(query, WqT, bq, qmb);
  passA_kernel<<<B_ * NTB, TPB, 0, stream>>>(features, amask, ftw,
                                             WtF, bfb, qmb, Wsg);
  passB_kernel<<<B_ * NTB, TPB, 0, stream>>>(values, WtV, bvb, Wsg, partials);
  tail_kernel<<<(B_ * Q_) / 64, TPB, 0, stream>>>(partials, WcT, bcb, Wout, bout, out);
}